// Round 1
// baseline (1142.203 us; speedup 1.0000x reference)
//
#include <hip/hip_runtime.h>
#include <hip/hip_bf16.h>
#include <math.h>

// Problem constants (fixed by the reference)
#define H_DIM   1024
#define I_DIM   512
#define NEXP    8
#define TOPK    2
#define NGROUP  4
#define T_TOK   4096
#define SCALE   1.0f

// Tiling
#define BT 32     // token rows per block
#define BN 64     // output cols per block
#define BK 64     // K tile
#define LDSP 68   // padded LDS row stride in floats (68*4 = 272 = 17*16B, float4-aligned)

// Workspace layout (bytes)
//  [0,64):           ecnt[8] (int)
//  [1024, +128K):    elist[8][4096]  (int, packed v = token*2 + slot)
//  [OFF_EW, +128K):  elist_w[8][4096] (float, routing weight)
//  [OFF_ACT, +16MB): act[8192][512]  (float, silu(g)*u per (token,slot) pair)
static constexpr size_t OFF_ECNT = 0;
static constexpr size_t OFF_ELIST = 1024;
static constexpr size_t OFF_EW    = OFF_ELIST + (size_t)NEXP * T_TOK * sizeof(int);
static constexpr size_t OFF_ACT   = 1u << 20;

// ---------------------------------------------------------------------------
// Gate: one wave per token. 8 dot products of length 1024, wave-reduced,
// then the grouped top-k routing on lane 0 (tiny scalar code, E=8).
// ---------------------------------------------------------------------------
__global__ __launch_bounds__(256)
void gate_kernel(const float* __restrict__ x,
                 const float* __restrict__ gw,
                 const float* __restrict__ bias,
                 int* __restrict__ ecnt,
                 int* __restrict__ elist,
                 float* __restrict__ elist_w) {
    const int wave = threadIdx.x >> 6;
    const int lane = threadIdx.x & 63;
    const int t = blockIdx.x * 4 + wave;
    if (t >= T_TOK) return;

    const float* xr = x + (size_t)t * H_DIM;
    float acc[NEXP];
#pragma unroll
    for (int e = 0; e < NEXP; ++e) acc[e] = 0.0f;

    for (int h = lane; h < H_DIM; h += 64) {
        const float xv = xr[h];
#pragma unroll
        for (int e = 0; e < NEXP; ++e)
            acc[e] = fmaf(xv, gw[e * H_DIM + h], acc[e]);
    }
#pragma unroll
    for (int e = 0; e < NEXP; ++e) {
        float v = acc[e];
#pragma unroll
        for (int s = 32; s > 0; s >>= 1) v += __shfl_xor(v, s, 64);
        acc[e] = v;
    }

    if (lane == 0) {
        float scores[NEXP], corr[NEXP];
#pragma unroll
        for (int e = 0; e < NEXP; ++e) {
            scores[e] = 1.0f / (1.0f + expf(-acc[e]));
            corr[e] = scores[e] + bias[e];
        }
        // group scores: gsz = E/NGROUP = 2 -> top-2 of 2 = sum of both
        float gs[NGROUP];
#pragma unroll
        for (int g = 0; g < NGROUP; ++g) gs[g] = corr[2 * g] + corr[2 * g + 1];
        // top-2 groups (ties -> lower index, matching jax.lax.top_k)
        int g0 = 0;
#pragma unroll
        for (int g = 1; g < NGROUP; ++g) if (gs[g] > gs[g0]) g0 = g;
        int g1 = -1;
#pragma unroll
        for (int g = 0; g < NGROUP; ++g) {
            if (g == g0) continue;
            if (g1 < 0 || gs[g] > gs[g1]) g1 = g;
        }
        // top-2 corrected scores among the 4 eligible experts
        int e0 = -1;
#pragma unroll
        for (int e = 0; e < NEXP; ++e) {
            const int g = e >> 1;
            if (g != g0 && g != g1) continue;
            if (e0 < 0 || corr[e] > corr[e0]) e0 = e;
        }
        int e1 = -1;
#pragma unroll
        for (int e = 0; e < NEXP; ++e) {
            const int g = e >> 1;
            if ((g != g0 && g != g1) || e == e0) continue;
            if (e1 < 0 || corr[e] > corr[e1]) e1 = e;
        }
        float w0 = scores[e0], w1 = scores[e1];
        const float inv = 1.0f / (w0 + w1 + 1e-20f);
        w0 *= inv * SCALE;
        w1 *= inv * SCALE;

        const int p0 = atomicAdd(&ecnt[e0], 1);
        elist[e0 * T_TOK + p0] = t * 2 + 0;
        elist_w[e0 * T_TOK + p0] = w0;
        const int p1 = atomicAdd(&ecnt[e1], 1);
        elist[e1 * T_TOK + p1] = t * 2 + 1;
        elist_w[e1 * T_TOK + p1] = w1;
    }
}

// ---------------------------------------------------------------------------
// GEMM1: per expert, gathered X tile vs gate_proj & up_proj (shared x tile),
// fused silu(g)*u, written to act[pairId][I].
// Block: 256 threads = (tx 16) x (ty 16); thread tile 2 tokens x 4 cols x 2 mats.
// ---------------------------------------------------------------------------
__global__ __launch_bounds__(256)
void gemm1_kernel(const float* __restrict__ x,
                  const float* __restrict__ wg_all,
                  const float* __restrict__ wu_all,
                  const int* __restrict__ ecnt,
                  const int* __restrict__ elist,
                  float* __restrict__ act) {
    const int e = blockIdx.z;
    const int cnt = ecnt[e];
    const int row0 = blockIdx.x * BT;
    if (row0 >= cnt) return;
    const int col0 = blockIdx.y * BN;

    __shared__ float xs[BT][LDSP];
    __shared__ float gsm[BN][LDSP];
    __shared__ float usm[BN][LDSP];
    __shared__ int rowv[BT];

    const int tid = threadIdx.x;
    const int tx = tid & 15;
    const int ty = tid >> 4;

    if (tid < BT) {
        const int r = row0 + tid;
        rowv[tid] = (r < cnt) ? elist[e * T_TOK + r] : -1;
    }

    const float* wg = wg_all + (size_t)e * I_DIM * H_DIM + (size_t)col0 * H_DIM;
    const float* wu = wu_all + (size_t)e * I_DIM * H_DIM + (size_t)col0 * H_DIM;

    float accg[2][4], accu[2][4];
#pragma unroll
    for (int a = 0; a < 2; ++a)
#pragma unroll
        for (int b = 0; b < 4; ++b) { accg[a][b] = 0.0f; accu[a][b] = 0.0f; }

    for (int k0 = 0; k0 < H_DIM; k0 += BK) {
        __syncthreads();
        // stage x tile: 32x64 floats = 2 float4/thread (gathered rows)
#pragma unroll
        for (int l = 0; l < 2; ++l) {
            const int idx = tid + l * 256;
            const int row = idx >> 4;
            const int kq = idx & 15;
            const int v = rowv[row];
            const int tt = (v >= 0) ? (v >> 1) : 0;
            *(float4*)&xs[row][kq * 4] =
                *(const float4*)(x + (size_t)tt * H_DIM + k0 + kq * 4);
        }
        // stage weight tiles: 64x64 floats each = 4 float4/thread each
#pragma unroll
        for (int l = 0; l < 4; ++l) {
            const int idx = tid + l * 256;
            const int row = idx >> 4;
            const int kq = idx & 15;
            *(float4*)&gsm[row][kq * 4] =
                *(const float4*)(wg + (size_t)row * H_DIM + k0 + kq * 4);
            *(float4*)&usm[row][kq * 4] =
                *(const float4*)(wu + (size_t)row * H_DIM + k0 + kq * 4);
        }
        __syncthreads();

#pragma unroll
        for (int k4 = 0; k4 < BK / 4; ++k4) {
            const float4 xv0 = *(const float4*)&xs[ty][k4 * 4];
            const float4 xv1 = *(const float4*)&xs[ty + 16][k4 * 4];
#pragma unroll
            for (int j = 0; j < 4; ++j) {
                const float4 g4 = *(const float4*)&gsm[tx + 16 * j][k4 * 4];
                const float4 u4 = *(const float4*)&usm[tx + 16 * j][k4 * 4];
                accg[0][j] = fmaf(xv0.x, g4.x, accg[0][j]);
                accg[0][j] = fmaf(xv0.y, g4.y, accg[0][j]);
                accg[0][j] = fmaf(xv0.z, g4.z, accg[0][j]);
                accg[0][j] = fmaf(xv0.w, g4.w, accg[0][j]);
                accg[1][j] = fmaf(xv1.x, g4.x, accg[1][j]);
                accg[1][j] = fmaf(xv1.y, g4.y, accg[1][j]);
                accg[1][j] = fmaf(xv1.z, g4.z, accg[1][j]);
                accg[1][j] = fmaf(xv1.w, g4.w, accg[1][j]);
                accu[0][j] = fmaf(xv0.x, u4.x, accu[0][j]);
                accu[0][j] = fmaf(xv0.y, u4.y, accu[0][j]);
                accu[0][j] = fmaf(xv0.z, u4.z, accu[0][j]);
                accu[0][j] = fmaf(xv0.w, u4.w, accu[0][j]);
                accu[1][j] = fmaf(xv1.x, u4.x, accu[1][j]);
                accu[1][j] = fmaf(xv1.y, u4.y, accu[1][j]);
                accu[1][j] = fmaf(xv1.z, u4.z, accu[1][j]);
                accu[1][j] = fmaf(xv1.w, u4.w, accu[1][j]);
            }
        }
    }

#pragma unroll
    for (int tk = 0; tk < 2; ++tk) {
        const int row = ty + 16 * tk;
        const int v = rowv[row];
        if (v < 0) continue;
        float* arow = act + (size_t)v * I_DIM + col0;
#pragma unroll
        for (int j = 0; j < 4; ++j) {
            const float g = accg[tk][j];
            const float u = accu[tk][j];
            const float s = g / (1.0f + expf(-g));  // silu
            arow[tx + 16 * j] = s * u;
        }
    }
}

// ---------------------------------------------------------------------------
// GEMM2: per expert, act rows vs down_proj; scaled atomicAdd into out.
// Each out element receives exactly TOPK=2 atomic adds -> deterministic.
// ---------------------------------------------------------------------------
__global__ __launch_bounds__(256)
void gemm2_kernel(const float* __restrict__ act,
                  const float* __restrict__ wd_all,
                  const int* __restrict__ ecnt,
                  const int* __restrict__ elist,
                  const float* __restrict__ elist_w,
                  float* __restrict__ out) {
    const int e = blockIdx.z;
    const int cnt = ecnt[e];
    const int row0 = blockIdx.x * BT;
    if (row0 >= cnt) return;
    const int col0 = blockIdx.y * BN;

    __shared__ float as[BT][LDSP];
    __shared__ float dsm[BN][LDSP];
    __shared__ int rowv[BT];
    __shared__ float roww[BT];

    const int tid = threadIdx.x;
    const int tx = tid & 15;
    const int ty = tid >> 4;

    if (tid < BT) {
        const int r = row0 + tid;
        if (r < cnt) {
            rowv[tid] = elist[e * T_TOK + r];
            roww[tid] = elist_w[e * T_TOK + r];
        } else {
            rowv[tid] = -1;
            roww[tid] = 0.0f;
        }
    }

    const float* wd = wd_all + (size_t)e * H_DIM * I_DIM + (size_t)col0 * I_DIM;

    float acc[2][4];
#pragma unroll
    for (int a = 0; a < 2; ++a)
#pragma unroll
        for (int b = 0; b < 4; ++b) acc[a][b] = 0.0f;

    for (int k0 = 0; k0 < I_DIM; k0 += BK) {
        __syncthreads();
#pragma unroll
        for (int l = 0; l < 2; ++l) {
            const int idx = tid + l * 256;
            const int row = idx >> 4;
            const int kq = idx & 15;
            const int v = rowv[row];
            const int ar = (v >= 0) ? v : 0;
            *(float4*)&as[row][kq * 4] =
                *(const float4*)(act + (size_t)ar * I_DIM + k0 + kq * 4);
        }
#pragma unroll
        for (int l = 0; l < 4; ++l) {
            const int idx = tid + l * 256;
            const int row = idx >> 4;
            const int kq = idx & 15;
            *(float4*)&dsm[row][kq * 4] =
                *(const float4*)(wd + (size_t)row * I_DIM + k0 + kq * 4);
        }
        __syncthreads();

#pragma unroll
        for (int k4 = 0; k4 < BK / 4; ++k4) {
            const float4 xv0 = *(const float4*)&as[ty][k4 * 4];
            const float4 xv1 = *(const float4*)&as[ty + 16][k4 * 4];
#pragma unroll
            for (int j = 0; j < 4; ++j) {
                const float4 d4 = *(const float4*)&dsm[tx + 16 * j][k4 * 4];
                acc[0][j] = fmaf(xv0.x, d4.x, acc[0][j]);
                acc[0][j] = fmaf(xv0.y, d4.y, acc[0][j]);
                acc[0][j] = fmaf(xv0.z, d4.z, acc[0][j]);
                acc[0][j] = fmaf(xv0.w, d4.w, acc[0][j]);
                acc[1][j] = fmaf(xv1.x, d4.x, acc[1][j]);
                acc[1][j] = fmaf(xv1.y, d4.y, acc[1][j]);
                acc[1][j] = fmaf(xv1.z, d4.z, acc[1][j]);
                acc[1][j] = fmaf(xv1.w, d4.w, acc[1][j]);
            }
        }
    }

#pragma unroll
    for (int tk = 0; tk < 2; ++tk) {
        const int row = ty + 16 * tk;
        const int v = rowv[row];
        if (v < 0) continue;
        const int t = v >> 1;
        const float w = roww[row];
        float* orow = out + (size_t)t * H_DIM + col0;
#pragma unroll
        for (int j = 0; j < 4; ++j)
            atomicAdd(&orow[tx + 16 * j], w * acc[tk][j]);
    }
}

// ---------------------------------------------------------------------------
extern "C" void kernel_launch(void* const* d_in, const int* in_sizes, int n_in,
                              void* d_out, int out_size, void* d_ws, size_t ws_size,
                              hipStream_t stream) {
    const float* x    = (const float*)d_in[0];  // [4,1024,1024]
    const float* gw   = (const float*)d_in[1];  // [8,1024]
    const float* bias = (const float*)d_in[2];  // [8]
    const float* wg   = (const float*)d_in[3];  // [8,512,1024]
    const float* wu   = (const float*)d_in[4];  // [8,512,1024]
    const float* wd   = (const float*)d_in[5];  // [8,1024,512]
    float* out = (float*)d_out;

    char* ws = (char*)d_ws;
    int*   ecnt    = (int*)(ws + OFF_ECNT);
    int*   elist   = (int*)(ws + OFF_ELIST);
    float* elist_w = (float*)(ws + OFF_EW);
    float* act     = (float*)(ws + OFF_ACT);

    hipMemsetAsync(ecnt, 0, 64, stream);
    hipMemsetAsync(out, 0, (size_t)out_size * sizeof(float), stream);

    gate_kernel<<<T_TOK / 4, 256, 0, stream>>>(x, gw, bias, ecnt, elist, elist_w);
    gemm1_kernel<<<dim3(T_TOK / BT, I_DIM / BN, NEXP), 256, 0, stream>>>(
        x, wg, wu, ecnt, elist, act);
    gemm2_kernel<<<dim3(T_TOK / BT, H_DIM / BN, NEXP), 256, 0, stream>>>(
        act, wd, ecnt, elist, elist_w, out);
}

// Round 2
// 428.255 us; speedup vs baseline: 2.6671x; 2.6671x over previous
//
#include <hip/hip_runtime.h>
#include <hip/hip_bf16.h>
#include <math.h>

// Problem constants (fixed by the reference)
#define H_DIM   1024
#define I_DIM   512
#define NEXP    8
#define NGROUP  4
#define T_TOK   4096
#define SCALE   1.0f

typedef float f32x4 __attribute__((ext_vector_type(4)));
typedef short bf16x8 __attribute__((ext_vector_type(8)));
typedef unsigned int u32;

// Workspace layout (bytes)
static constexpr size_t OFF_ECNT  = 0;
static constexpr size_t OFF_ELIST = 1024;
static constexpr size_t OFF_EW    = OFF_ELIST + (size_t)NEXP * T_TOK * sizeof(int);
static constexpr size_t OFF_ACT   = 1u << 20;   // act[8192][512] f32 = 16.8 MB

// ---------------------------------------------------------------------------
// async 16B global->LDS
// ---------------------------------------------------------------------------
__device__ __forceinline__ void gl_lds16(void* lds, const void* g) {
    __builtin_amdgcn_global_load_lds(
        (const __attribute__((address_space(1))) u32*)g,
        (__attribute__((address_space(3))) u32*)lds, 16, 0, 0);
}

// fp32 -> (hi trunc-bf16, lo bf16 of residual); residual error ~2^-16 relative
__device__ __forceinline__ void cvt8(const f32x4& a, const f32x4& b,
                                     bf16x8& hi, bf16x8& lo) {
#pragma unroll
    for (int j = 0; j < 4; ++j) {
        const u32 xb = __float_as_uint(a[j]);
        hi[j] = (short)(xb >> 16);
        const float r = a[j] - __uint_as_float(xb & 0xffff0000u);
        lo[j] = (short)(__float_as_uint(r) >> 16);
    }
#pragma unroll
    for (int j = 0; j < 4; ++j) {
        const u32 xb = __float_as_uint(b[j]);
        hi[4 + j] = (short)(xb >> 16);
        const float r = b[j] - __uint_as_float(xb & 0xffff0000u);
        lo[4 + j] = (short)(__float_as_uint(r) >> 16);
    }
}

// load one 8-elem fp32 fragment row from a swizzled [64][64] f32 LDS tile
// off1 = ((ksub*128 + laneQ*32) ^ (laneR<<4));  row multiple-of-16 base + laneR
__device__ __forceinline__ void frag_ld(const float* tile, int row, int off1,
                                        bf16x8& hi, bf16x8& lo) {
    const char* p = (const char*)tile + row * 256;
    const f32x4 a = *(const f32x4*)(p + off1);
    const f32x4 b = *(const f32x4*)(p + (off1 ^ 16));
    cvt8(a, b, hi, lo);
}

// split-bf16 triple MFMA: acc += Ah*Bh + Ah*Bl + Al*Bh
__device__ __forceinline__ f32x4 mmac3(bf16x8 ah, bf16x8 al, bf16x8 bh,
                                       bf16x8 bl, f32x4 c) {
    c = __builtin_amdgcn_mfma_f32_16x16x32_bf16(ah, bh, c, 0, 0, 0);
    c = __builtin_amdgcn_mfma_f32_16x16x32_bf16(ah, bl, c, 0, 0, 0);
    c = __builtin_amdgcn_mfma_f32_16x16x32_bf16(al, bh, c, 0, 0, 0);
    return c;
}

// ---------------------------------------------------------------------------
// Gate: one wave per token (unchanged from validated baseline)
// ---------------------------------------------------------------------------
__global__ __launch_bounds__(256)
void gate_kernel(const float* __restrict__ x,
                 const float* __restrict__ gw,
                 const float* __restrict__ bias,
                 int* __restrict__ ecnt,
                 int* __restrict__ elist,
                 float* __restrict__ elist_w) {
    const int wave = threadIdx.x >> 6;
    const int lane = threadIdx.x & 63;
    const int t = blockIdx.x * 4 + wave;
    if (t >= T_TOK) return;

    const float* xr = x + (size_t)t * H_DIM;
    float acc[NEXP];
#pragma unroll
    for (int e = 0; e < NEXP; ++e) acc[e] = 0.0f;

    for (int h = lane; h < H_DIM; h += 64) {
        const float xv = xr[h];
#pragma unroll
        for (int e = 0; e < NEXP; ++e)
            acc[e] = fmaf(xv, gw[e * H_DIM + h], acc[e]);
    }
#pragma unroll
    for (int e = 0; e < NEXP; ++e) {
        float v = acc[e];
#pragma unroll
        for (int s = 32; s > 0; s >>= 1) v += __shfl_xor(v, s, 64);
        acc[e] = v;
    }

    if (lane == 0) {
        float scores[NEXP], corr[NEXP];
#pragma unroll
        for (int e = 0; e < NEXP; ++e) {
            scores[e] = 1.0f / (1.0f + expf(-acc[e]));
            corr[e] = scores[e] + bias[e];
        }
        float gs[NGROUP];
#pragma unroll
        for (int g = 0; g < NGROUP; ++g) gs[g] = corr[2 * g] + corr[2 * g + 1];
        int g0 = 0;
#pragma unroll
        for (int g = 1; g < NGROUP; ++g) if (gs[g] > gs[g0]) g0 = g;
        int g1 = -1;
#pragma unroll
        for (int g = 0; g < NGROUP; ++g) {
            if (g == g0) continue;
            if (g1 < 0 || gs[g] > gs[g1]) g1 = g;
        }
        int e0 = -1;
#pragma unroll
        for (int e = 0; e < NEXP; ++e) {
            const int g = e >> 1;
            if (g != g0 && g != g1) continue;
            if (e0 < 0 || corr[e] > corr[e0]) e0 = e;
        }
        int e1 = -1;
#pragma unroll
        for (int e = 0; e < NEXP; ++e) {
            const int g = e >> 1;
            if ((g != g0 && g != g1) || e == e0) continue;
            if (e1 < 0 || corr[e] > corr[e1]) e1 = e;
        }
        float w0 = scores[e0], w1 = scores[e1];
        const float inv = 1.0f / (w0 + w1 + 1e-20f);
        w0 *= inv * SCALE;
        w1 *= inv * SCALE;

        const int p0 = atomicAdd(&ecnt[e0], 1);
        elist[e0 * T_TOK + p0] = t * 2 + 0;
        elist_w[e0 * T_TOK + p0] = w0;
        const int p1 = atomicAdd(&ecnt[e1], 1);
        elist[e1 * T_TOK + p1] = t * 2 + 1;
        elist_w[e1 * T_TOK + p1] = w1;
    }
}

// ---------------------------------------------------------------------------
// GEMM1 (MFMA split-bf16): gathered X vs gate_proj & up_proj, fused silu*up.
// Block: 256 thr = 4 waves (2x2). Tile 64 rows x 64 cols (per matrix), BK=64.
// LDS tiles are fp32 [64][64], XOR-swizzled byte^=(row&15)<<4, staged via
// global_load_lds with pre-swizzled source chunks.
// ---------------------------------------------------------------------------
__global__ __launch_bounds__(256)
void gemm1_mfma(const float* __restrict__ x,
                const float* __restrict__ wg_all,
                const float* __restrict__ wu_all,
                const int* __restrict__ ecnt,
                const int* __restrict__ elist,
                float* __restrict__ act) {
    const int e = blockIdx.z;
    const int cnt = ecnt[e];
    const int row0 = blockIdx.x * 64;
    if (row0 >= cnt) return;
    const int col0 = blockIdx.y * 64;

    __shared__ float xs[64 * 64];
    __shared__ float gsm[64 * 64];
    __shared__ float usm[64 * 64];

    const int tid = threadIdx.x;
    const int lane = tid & 63;
    const int wv = tid >> 6;
    const int wr = wv >> 1, wc = wv & 1;
    const int laneR = lane & 15, laneQ = lane >> 4;

    const int* el = elist + e * T_TOK;

    // per-thread staging descriptors (4 x 16B chunks per tile)
    const float* xrow[4];
    const float* grow[4];
    const float* urow[4];
    int coff[4], ldso[4];
#pragma unroll
    for (int l = 0; l < 4; ++l) {
        const int ci = tid + l * 256;
        const int row = ci >> 4;
        const int c = (ci & 15) ^ (row & 15);   // pre-swizzled source chunk
        coff[l] = c * 4;                        // float offset within row
        ldso[l] = ci * 16;                      // linear LDS byte offset
        const int rr = row0 + row;
        const int v = (rr < cnt) ? el[rr] : 0;
        xrow[l] = x + (size_t)(v >> 1) * H_DIM;
        grow[l] = wg_all + (size_t)e * I_DIM * H_DIM + (size_t)(col0 + row) * H_DIM;
        urow[l] = wu_all + (size_t)e * I_DIM * H_DIM + (size_t)(col0 + row) * H_DIM;
    }

    f32x4 ag[2][2], au[2][2];
#pragma unroll
    for (int m = 0; m < 2; ++m)
#pragma unroll
        for (int n = 0; n < 2; ++n) {
            ag[m][n] = (f32x4)0.0f;
            au[m][n] = (f32x4)0.0f;
        }

    for (int k0 = 0; k0 < H_DIM; k0 += 64) {
        __syncthreads();   // previous tile fully consumed
#pragma unroll
        for (int l = 0; l < 4; ++l) {
            gl_lds16((char*)xs + ldso[l], xrow[l] + k0 + coff[l]);
            gl_lds16((char*)gsm + ldso[l], grow[l] + k0 + coff[l]);
            gl_lds16((char*)usm + ldso[l], urow[l] + k0 + coff[l]);
        }
        __syncthreads();   // drains vmcnt -> tile ready

#pragma unroll
        for (int ks = 0; ks < 2; ++ks) {
            const int off1 = ((ks * 128 + laneQ * 32) ^ (laneR << 4));
            bf16x8 xh[2], xl[2];
#pragma unroll
            for (int m = 0; m < 2; ++m)
                frag_ld(xs, wr * 32 + m * 16 + laneR, off1, xh[m], xl[m]);
            bf16x8 gh[2], gl[2], uh[2], ul[2];
#pragma unroll
            for (int n = 0; n < 2; ++n) {
                frag_ld(gsm, wc * 32 + n * 16 + laneR, off1, gh[n], gl[n]);
                frag_ld(usm, wc * 32 + n * 16 + laneR, off1, uh[n], ul[n]);
            }
#pragma unroll
            for (int m = 0; m < 2; ++m)
#pragma unroll
                for (int n = 0; n < 2; ++n) {
                    ag[m][n] = mmac3(xh[m], xl[m], gh[n], gl[n], ag[m][n]);
                    au[m][n] = mmac3(xh[m], xl[m], uh[n], ul[n], au[m][n]);
                }
        }
    }

    // epilogue: C/D map col=lane&15, row=(lane>>4)*4+j (m89-verified)
#pragma unroll
    for (int m = 0; m < 2; ++m) {
        const int rl = wr * 32 + m * 16 + laneQ * 4;
#pragma unroll
        for (int j = 0; j < 4; ++j) {
            const int rr = row0 + rl + j;
            if (rr >= cnt) continue;
            const int v = el[rr];
            float* arow = act + (size_t)v * I_DIM;
#pragma unroll
            for (int n = 0; n < 2; ++n) {
                const int col = col0 + wc * 32 + n * 16 + laneR;
                const float g = ag[m][n][j];
                const float u = au[m][n][j];
                const float s = g / (1.0f + __expf(-g));
                arow[col] = s * u;
            }
        }
    }
}

// ---------------------------------------------------------------------------
// GEMM2 (MFMA split-bf16): act rows vs down_proj, scaled atomicAdd into out.
// ---------------------------------------------------------------------------
__global__ __launch_bounds__(256)
void gemm2_mfma(const float* __restrict__ act,
                const float* __restrict__ wd_all,
                const int* __restrict__ ecnt,
                const int* __restrict__ elist,
                const float* __restrict__ elist_w,
                float* __restrict__ out) {
    const int e = blockIdx.z;
    const int cnt = ecnt[e];
    const int row0 = blockIdx.x * 64;
    if (row0 >= cnt) return;
    const int col0 = blockIdx.y * 64;

    __shared__ float as[64 * 64];
    __shared__ float dsm[64 * 64];

    const int tid = threadIdx.x;
    const int lane = tid & 63;
    const int wv = tid >> 6;
    const int wr = wv >> 1, wc = wv & 1;
    const int laneR = lane & 15, laneQ = lane >> 4;

    const int* el = elist + e * T_TOK;
    const float* elw = elist_w + e * T_TOK;

    const float* arow[4];
    const float* drow[4];
    int coff[4], ldso[4];
#pragma unroll
    for (int l = 0; l < 4; ++l) {
        const int ci = tid + l * 256;
        const int row = ci >> 4;
        const int c = (ci & 15) ^ (row & 15);
        coff[l] = c * 4;
        ldso[l] = ci * 16;
        const int rr = row0 + row;
        const int v = (rr < cnt) ? el[rr] : 0;
        arow[l] = act + (size_t)v * I_DIM;
        drow[l] = wd_all + (size_t)e * H_DIM * I_DIM + (size_t)(col0 + row) * I_DIM;
    }

    f32x4 acc[2][2];
#pragma unroll
    for (int m = 0; m < 2; ++m)
#pragma unroll
        for (int n = 0; n < 2; ++n) acc[m][n] = (f32x4)0.0f;

    for (int k0 = 0; k0 < I_DIM; k0 += 64) {
        __syncthreads();
#pragma unroll
        for (int l = 0; l < 4; ++l) {
            gl_lds16((char*)as + ldso[l], arow[l] + k0 + coff[l]);
            gl_lds16((char*)dsm + ldso[l], drow[l] + k0 + coff[l]);
        }
        __syncthreads();

#pragma unroll
        for (int ks = 0; ks < 2; ++ks) {
            const int off1 = ((ks * 128 + laneQ * 32) ^ (laneR << 4));
            bf16x8 ah[2], al[2];
#pragma unroll
            for (int m = 0; m < 2; ++m)
                frag_ld(as, wr * 32 + m * 16 + laneR, off1, ah[m], al[m]);
            bf16x8 bh[2], bl[2];
#pragma unroll
            for (int n = 0; n < 2; ++n)
                frag_ld(dsm, wc * 32 + n * 16 + laneR, off1, bh[n], bl[n]);
#pragma unroll
            for (int m = 0; m < 2; ++m)
#pragma unroll
                for (int n = 0; n < 2; ++n)
                    acc[m][n] = mmac3(ah[m], al[m], bh[n], bl[n], acc[m][n]);
        }
    }

#pragma unroll
    for (int m = 0; m < 2; ++m) {
        const int rl = wr * 32 + m * 16 + laneQ * 4;
#pragma unroll
        for (int j = 0; j < 4; ++j) {
            const int rr = row0 + rl + j;
            if (rr >= cnt) continue;
            const int v = el[rr];
            const float w = elw[rr];
            const int t = v >> 1;
            float* orow = out + (size_t)t * H_DIM;
#pragma unroll
            for (int n = 0; n < 2; ++n) {
                const int col = col0 + wc * 32 + n * 16 + laneR;
                atomicAdd(&orow[col], w * acc[m][n][j]);
            }
        }
    }
}

// ---------------------------------------------------------------------------
extern "C" void kernel_launch(void* const* d_in, const int* in_sizes, int n_in,
                              void* d_out, int out_size, void* d_ws, size_t ws_size,
                              hipStream_t stream) {
    const float* x    = (const float*)d_in[0];  // [4,1024,1024]
    const float* gw   = (const float*)d_in[1];  // [8,1024]
    const float* bias = (const float*)d_in[2];  // [8]
    const float* wg   = (const float*)d_in[3];  // [8,512,1024]
    const float* wu   = (const float*)d_in[4];  // [8,512,1024]
    const float* wd   = (const float*)d_in[5];  // [8,1024,512]
    float* out = (float*)d_out;

    char* ws = (char*)d_ws;
    int*   ecnt    = (int*)(ws + OFF_ECNT);
    int*   elist   = (int*)(ws + OFF_ELIST);
    float* elist_w = (float*)(ws + OFF_EW);
    float* act     = (float*)(ws + OFF_ACT);

    hipMemsetAsync(ecnt, 0, 64, stream);
    hipMemsetAsync(out, 0, (size_t)out_size * sizeof(float), stream);

    gate_kernel<<<T_TOK / 4, 256, 0, stream>>>(x, gw, bias, ecnt, elist, elist_w);
    gemm1_mfma<<<dim3(T_TOK / 64, I_DIM / 64, NEXP), 256, 0, stream>>>(
        x, wg, wu, ecnt, elist, act);
    gemm2_mfma<<<dim3(T_TOK / 64, H_DIM / 64, NEXP), 256, 0, stream>>>(
        act, wd, ecnt, elist, elist_w, out);
}

// Round 7
// 373.633 us; speedup vs baseline: 3.0570x; 1.1462x over previous
//
#include <hip/hip_runtime.h>
#include <hip/hip_bf16.h>
#include <math.h>

// Problem constants (fixed by the reference)
#define H_DIM   1024
#define I_DIM   512
#define NEXP    8
#define NGROUP  4
#define T_TOK   4096
#define NPAIR   8192
#define SCALE   1.0f

typedef float f32x4 __attribute__((ext_vector_type(4)));
typedef short bf16x8 __attribute__((ext_vector_type(8)));
typedef short s16x4 __attribute__((ext_vector_type(4)));
typedef unsigned int u32;

// ---------------- workspace layout (fast path), bytes ----------------
static constexpr size_t OFF_ECNT  = 0;                        // 64 B
static constexpr size_t OFF_ELIST = 1024;                     // 128 KB
static constexpr size_t OFF_EW    = OFF_ELIST + (size_t)NEXP * T_TOK * 4;
static constexpr size_t MB = 1u << 20;
static constexpr size_t OFF_XH   = 1 * MB;   // 4096x1024 bf16 = 8 MB
static constexpr size_t OFF_XL   = 9 * MB;
static constexpr size_t OFF_WGH  = 17 * MB;  // 8x512x1024 bf16 = 8 MB each
static constexpr size_t OFF_WGL  = 25 * MB;
static constexpr size_t OFF_WUH  = 33 * MB;
static constexpr size_t OFF_WUL  = 41 * MB;
static constexpr size_t OFF_WDH  = 49 * MB;  // 8x1024x512
static constexpr size_t OFF_WDL  = 57 * MB;
static constexpr size_t OFF_ACTH = 65 * MB;  // 8192x512 bf16 = 8 MB
static constexpr size_t OFF_ACTL = 73 * MB;
static constexpr size_t WS_NEED  = 81 * MB;
// fallback (R2) layout
static constexpr size_t OFF_ACT_FB = 1 * MB; // 8192x512 f32 = 16.8 MB

// ---------------------------------------------------------------------------
__device__ __forceinline__ void gl_lds16(void* lds, const void* g) {
    __builtin_amdgcn_global_load_lds(
        (const __attribute__((address_space(1))) u32*)g,
        (__attribute__((address_space(3))) u32*)lds, 16, 0, 0);
}

__device__ __forceinline__ void split1(float v, short& h, short& l) {
    const u32 b = __float_as_uint(v);
    h = (short)(b >> 16);
    const float r = v - __uint_as_float(b & 0xffff0000u);
    l = (short)(__float_as_uint(r) >> 16);
}

// split-bf16 triple MFMA: acc += Ah*Bh + Ah*Bl + Al*Bh
__device__ __forceinline__ f32x4 mmac3(bf16x8 ah, bf16x8 al, bf16x8 bh,
                                       bf16x8 bl, f32x4 c) {
    c = __builtin_amdgcn_mfma_f32_16x16x32_bf16(ah, bh, c, 0, 0, 0);
    c = __builtin_amdgcn_mfma_f32_16x16x32_bf16(ah, bl, c, 0, 0, 0);
    c = __builtin_amdgcn_mfma_f32_16x16x32_bf16(al, bh, c, 0, 0, 0);
    return c;
}

// read one bf16x8 fragment from a swizzled [64][64] bf16 LDS tile (128B rows)
__device__ __forceinline__ bf16x8 frag16(const short* tile, int row, int boff) {
    return *(const bf16x8*)((const char*)tile + row * 128 + boff);
}

// ---------------------------------------------------------------------------
// Fast path: x conversion to hi/lo planes + gate routing, fused (one x pass)
// ---------------------------------------------------------------------------
__global__ __launch_bounds__(256)
void cvt_x_gate(const float* __restrict__ x,
                const float* __restrict__ gw,
                const float* __restrict__ bias,
                short* __restrict__ xh, short* __restrict__ xl,
                int* __restrict__ ecnt, int* __restrict__ elist,
                float* __restrict__ elist_w) {
    const int t = blockIdx.x;
    const int tid = threadIdx.x;
    const int lane = tid & 63;
    const int wv = tid >> 6;
    const int h = tid * 4;

    const f32x4 xv = *(const f32x4*)(x + (size_t)t * H_DIM + h);
    s16x4 hv, lv;
#pragma unroll
    for (int j = 0; j < 4; ++j) {
        short hh, ll;
        split1(xv[j], hh, ll);
        hv[j] = hh;
        lv[j] = ll;
    }
    *(s16x4*)(xh + (size_t)t * H_DIM + h) = hv;
    *(s16x4*)(xl + (size_t)t * H_DIM + h) = lv;

    float acc[NEXP];
#pragma unroll
    for (int e = 0; e < NEXP; ++e) {
        const f32x4 g = *(const f32x4*)(gw + e * H_DIM + h);
        float a = xv[0] * g[0];
        a = fmaf(xv[1], g[1], a);
        a = fmaf(xv[2], g[2], a);
        a = fmaf(xv[3], g[3], a);
        acc[e] = a;
    }
#pragma unroll
    for (int e = 0; e < NEXP; ++e) {
        float v = acc[e];
#pragma unroll
        for (int s = 32; s > 0; s >>= 1) v += __shfl_xor(v, s, 64);
        acc[e] = v;
    }
    __shared__ float red[4][NEXP];
    if (lane == 0) {
#pragma unroll
        for (int e = 0; e < NEXP; ++e) red[wv][e] = acc[e];
    }
    __syncthreads();
    if (tid == 0) {
        float scores[NEXP], corr[NEXP];
#pragma unroll
        for (int e = 0; e < NEXP; ++e) {
            const float s = red[0][e] + red[1][e] + red[2][e] + red[3][e];
            scores[e] = 1.0f / (1.0f + expf(-s));
            corr[e] = scores[e] + bias[e];
        }
        float gs[NGROUP];
#pragma unroll
        for (int g = 0; g < NGROUP; ++g) gs[g] = corr[2 * g] + corr[2 * g + 1];
        int g0 = 0;
#pragma unroll
        for (int g = 1; g < NGROUP; ++g) if (gs[g] > gs[g0]) g0 = g;
        int g1 = -1;
#pragma unroll
        for (int g = 0; g < NGROUP; ++g) {
            if (g == g0) continue;
            if (g1 < 0 || gs[g] > gs[g1]) g1 = g;
        }
        int e0 = -1;
#pragma unroll
        for (int e = 0; e < NEXP; ++e) {
            const int g = e >> 1;
            if (g != g0 && g != g1) continue;
            if (e0 < 0 || corr[e] > corr[e0]) e0 = e;
        }
        int e1 = -1;
#pragma unroll
        for (int e = 0; e < NEXP; ++e) {
            const int g = e >> 1;
            if ((g != g0 && g != g1) || e == e0) continue;
            if (e1 < 0 || corr[e] > corr[e1]) e1 = e;
        }
        float w0 = scores[e0], w1 = scores[e1];
        const float inv = 1.0f / (w0 + w1 + 1e-20f);
        w0 *= inv * SCALE;
        w1 *= inv * SCALE;
        const int p0 = atomicAdd(&ecnt[e0], 1);
        elist[e0 * T_TOK + p0] = t * 2 + 0;
        elist_w[e0 * T_TOK + p0] = w0;
        const int p1 = atomicAdd(&ecnt[e1], 1);
        elist[e1 * T_TOK + p1] = t * 2 + 1;
        elist_w[e1 * T_TOK + p1] = w1;
    }
}

// elementwise fp32 -> bf16 hi/lo planes (weights); n multiple of 1024
__global__ __launch_bounds__(256)
void cvt_w_kernel(const float* __restrict__ src, short* __restrict__ h,
                  short* __restrict__ l, int n) {
    const int i = (blockIdx.x * 256 + threadIdx.x) * 4;
    if (i >= n) return;
    const f32x4 v = *(const f32x4*)(src + i);
    s16x4 hv, lv;
#pragma unroll
    for (int j = 0; j < 4; ++j) {
        short hh, ll;
        split1(v[j], hh, ll);
        hv[j] = hh;
        lv[j] = ll;
    }
    *(s16x4*)(h + i) = hv;
    *(s16x4*)(l + i) = lv;
}

// ---------------------------------------------------------------------------
// GEMM1 planar: gathered x (hi/lo) vs gate/up (hi/lo), fused silu*up,
// act written as hi/lo bf16 planes. 4 waves (2x2), tile 64x64, BK=64.
// ---------------------------------------------------------------------------
__global__ __launch_bounds__(256)
void gemm1_planar(const short* __restrict__ xh, const short* __restrict__ xl,
                  const short* __restrict__ wgh, const short* __restrict__ wgl,
                  const short* __restrict__ wuh, const short* __restrict__ wul,
                  const int* __restrict__ ecnt, const int* __restrict__ elist,
                  short* __restrict__ acth, short* __restrict__ actl) {
    const int e = blockIdx.z;
    const int cnt = ecnt[e];
    const int row0 = blockIdx.x * 64;
    if (row0 >= cnt) return;
    const int col0 = blockIdx.y * 64;

    __shared__ __align__(16) short xhb[4096], xlb[4096];
    __shared__ __align__(16) short ghb[4096], glb[4096];
    __shared__ __align__(16) short uhb[4096], ulb[4096];

    const int tid = threadIdx.x, lane = tid & 63, wv = tid >> 6;
    const int wr = wv >> 1, wc = wv & 1;
    const int laneR = lane & 15, laneQ = lane >> 4;
    const int* el = elist + e * T_TOK;

    size_t xoff[2], woff[2];
    int ldso[2];
#pragma unroll
    for (int l = 0; l < 2; ++l) {
        const int ci = tid + l * 256;
        const int row = ci >> 3;
        const int c = (ci & 7) ^ (row & 7);     // pre-swizzled source chunk
        ldso[l] = ci * 16;
        const int rr = row0 + row;
        const int v = (rr < cnt) ? el[rr] : 0;
        xoff[l] = (size_t)(v >> 1) * H_DIM + c * 8;
        woff[l] = ((size_t)e * I_DIM + col0 + row) * H_DIM + c * 8;
    }

    f32x4 ag[2][2], au[2][2];
#pragma unroll
    for (int m = 0; m < 2; ++m)
#pragma unroll
        for (int n = 0; n < 2; ++n) { ag[m][n] = (f32x4)0.0f; au[m][n] = (f32x4)0.0f; }

    for (int k0 = 0; k0 < H_DIM; k0 += 64) {
        __syncthreads();
#pragma unroll
        for (int l = 0; l < 2; ++l) {
            gl_lds16((char*)xhb + ldso[l], xh + xoff[l] + k0);
            gl_lds16((char*)xlb + ldso[l], xl + xoff[l] + k0);
            gl_lds16((char*)ghb + ldso[l], wgh + woff[l] + k0);
            gl_lds16((char*)glb + ldso[l], wgl + woff[l] + k0);
            gl_lds16((char*)uhb + ldso[l], wuh + woff[l] + k0);
            gl_lds16((char*)ulb + ldso[l], wul + woff[l] + k0);
        }
        __syncthreads();

#pragma unroll
        for (int ks = 0; ks < 2; ++ks) {
            const int boff = (ks * 64 + laneQ * 16) ^ ((laneR & 7) << 4);
            bf16x8 xh_[2], xl_[2];
#pragma unroll
            for (int m = 0; m < 2; ++m) {
                const int r = wr * 32 + m * 16 + laneR;
                xh_[m] = frag16(xhb, r, boff);
                xl_[m] = frag16(xlb, r, boff);
            }
            bf16x8 gh_[2], gl_[2], uh_[2], ul_[2];
#pragma unroll
            for (int n = 0; n < 2; ++n) {
                const int r = wc * 32 + n * 16 + laneR;
                gh_[n] = frag16(ghb, r, boff);
                gl_[n] = frag16(glb, r, boff);
                uh_[n] = frag16(uhb, r, boff);
                ul_[n] = frag16(ulb, r, boff);
            }
#pragma unroll
            for (int m = 0; m < 2; ++m)
#pragma unroll
                for (int n = 0; n < 2; ++n) {
                    ag[m][n] = mmac3(xh_[m], xl_[m], gh_[n], gl_[n], ag[m][n]);
                    au[m][n] = mmac3(xh_[m], xl_[m], uh_[n], ul_[n], au[m][n]);
                }
        }
    }

    // C/D map: col=lane&15, row=(lane>>4)*4+j (verified in R2)
#pragma unroll
    for (int m = 0; m < 2; ++m) {
        const int rl = wr * 32 + m * 16 + laneQ * 4;
#pragma unroll
        for (int j = 0; j < 4; ++j) {
            const int rr = row0 + rl + j;
            if (rr >= cnt) continue;
            const int v = el[rr];
#pragma unroll
            for (int n = 0; n < 2; ++n) {
                const int col = col0 + wc * 32 + n * 16 + laneR;
                const float g = ag[m][n][j];
                const float u = au[m][n][j];
                const float val = (g / (1.0f + __expf(-g))) * u;
                short hh, ll;
                split1(val, hh, ll);
                acth[(size_t)v * I_DIM + col] = hh;
                actl[(size_t)v * I_DIM + col] = ll;
            }
        }
    }
}

// ---------------------------------------------------------------------------
// GEMM2 planar: act (hi/lo) vs down_proj (hi/lo), scaled atomicAdd into out.
// ---------------------------------------------------------------------------
__global__ __launch_bounds__(256)
void gemm2_planar(const short* __restrict__ acth, const short* __restrict__ actl,
                  const short* __restrict__ wdh, const short* __restrict__ wdl,
                  const int* __restrict__ ecnt, const int* __restrict__ elist,
                  const float* __restrict__ elist_w, float* __restrict__ out) {
    const int e = blockIdx.z;
    const int cnt = ecnt[e];
    const int row0 = blockIdx.x * 64;
    if (row0 >= cnt) return;
    const int col0 = blockIdx.y * 64;

    __shared__ __align__(16) short ahb[4096], alb[4096];
    __shared__ __align__(16) short dhb[4096], dlb[4096];

    const int tid = threadIdx.x, lane = tid & 63, wv = tid >> 6;
    const int wr = wv >> 1, wc = wv & 1;
    const int laneR = lane & 15, laneQ = lane >> 4;
    const int* el = elist + e * T_TOK;
    const float* elw = elist_w + e * T_TOK;

    size_t aoff[2], woff[2];
    int ldso[2];
#pragma unroll
    for (int l = 0; l < 2; ++l) {
        const int ci = tid + l * 256;
        const int row = ci >> 3;
        const int c = (ci & 7) ^ (row & 7);
        ldso[l] = ci * 16;
        const int rr = row0 + row;
        const int v = (rr < cnt) ? el[rr] : 0;
        aoff[l] = (size_t)v * I_DIM + c * 8;
        woff[l] = ((size_t)e * H_DIM + col0 + row) * I_DIM + c * 8;
    }

    f32x4 acc[2][2];
#pragma unroll
    for (int m = 0; m < 2; ++m)
#pragma unroll
        for (int n = 0; n < 2; ++n) acc[m][n] = (f32x4)0.0f;

    for (int k0 = 0; k0 < I_DIM; k0 += 64) {
        __syncthreads();
#pragma unroll
        for (int l = 0; l < 2; ++l) {
            gl_lds16((char*)ahb + ldso[l], acth + aoff[l] + k0);
            gl_lds16((char*)alb + ldso[l], actl + aoff[l] + k0);
            gl_lds16((char*)dhb + ldso[l], wdh + woff[l] + k0);
            gl_lds16((char*)dlb + ldso[l], wdl + woff[l] + k0);
        }
        __syncthreads();

#pragma unroll
        for (int ks = 0; ks < 2; ++ks) {
            const int boff = (ks * 64 + laneQ * 16) ^ ((laneR & 7) << 4);
            bf16x8 ah_[2], al_[2];
#pragma unroll
            for (int m = 0; m < 2; ++m) {
                const int r = wr * 32 + m * 16 + laneR;
                ah_[m] = frag16(ahb, r, boff);
                al_[m] = frag16(alb, r, boff);
            }
            bf16x8 bh_[2], bl_[2];
#pragma unroll
            for (int n = 0; n < 2; ++n) {
                const int r = wc * 32 + n * 16 + laneR;
                bh_[n] = frag16(dhb, r, boff);
                bl_[n] = frag16(dlb, r, boff);
            }
#pragma unroll
            for (int m = 0; m < 2; ++m)
#pragma unroll
                for (int n = 0; n < 2; ++n)
                    acc[m][n] = mmac3(ah_[m], al_[m], bh_[n], bl_[n], acc[m][n]);
        }
    }

#pragma unroll
    for (int m = 0; m < 2; ++m) {
        const int rl = wr * 32 + m * 16 + laneQ * 4;
#pragma unroll
        for (int j = 0; j < 4; ++j) {
            const int rr = row0 + rl + j;
            if (rr >= cnt) continue;
            const int v = el[rr];
            const float w = elw[rr];
            float* orow = out + (size_t)(v >> 1) * H_DIM;
#pragma unroll
            for (int n = 0; n < 2; ++n) {
                const int col = col0 + wc * 32 + n * 16 + laneR;
                atomicAdd(&orow[col], w * acc[m][n][j]);
            }
        }
    }
}

// ===========================================================================
// Fallback path (R2, verified): used only if ws_size < WS_NEED
// ===========================================================================
__device__ __forceinline__ void cvt8(const f32x4& a, const f32x4& b,
                                     bf16x8& hi, bf16x8& lo) {
#pragma unroll
    for (int j = 0; j < 4; ++j) {
        short hh, ll;
        split1(a[j], hh, ll);
        ((short*)&hi)[j] = hh;
        ((short*)&lo)[j] = ll;
    }
#pragma unroll
    for (int j = 0; j < 4; ++j) {
        short hh, ll;
        split1(b[j], hh, ll);
        ((short*)&hi)[4 + j] = hh;
        ((short*)&lo)[4 + j] = ll;
    }
}

__device__ __forceinline__ void frag_ld(const float* tile, int row, int off1,
                                        bf16x8& hi, bf16x8& lo) {
    const char* p = (const char*)tile + row * 256;
    const f32x4 a = *(const f32x4*)(p + off1);
    const f32x4 b = *(const f32x4*)(p + (off1 ^ 16));
    cvt8(a, b, hi, lo);
}

__global__ __launch_bounds__(256)
void gate_kernel(const float* __restrict__ x, const float* __restrict__ gw,
                 const float* __restrict__ bias, int* __restrict__ ecnt,
                 int* __restrict__ elist, float* __restrict__ elist_w) {
    const int wave = threadIdx.x >> 6;
    const int lane = threadIdx.x & 63;
    const int t = blockIdx.x * 4 + wave;
    if (t >= T_TOK) return;
    const float* xr = x + (size_t)t * H_DIM;
    float acc[NEXP];
#pragma unroll
    for (int e = 0; e < NEXP; ++e) acc[e] = 0.0f;
    for (int h = lane; h < H_DIM; h += 64) {
        const float xv = xr[h];
#pragma unroll
        for (int e = 0; e < NEXP; ++e) acc[e] = fmaf(xv, gw[e * H_DIM + h], acc[e]);
    }
#pragma unroll
    for (int e = 0; e < NEXP; ++e) {
        float v = acc[e];
#pragma unroll
        for (int s = 32; s > 0; s >>= 1) v += __shfl_xor(v, s, 64);
        acc[e] = v;
    }
    if (lane == 0) {
        float scores[NEXP], corr[NEXP];
#pragma unroll
        for (int e = 0; e < NEXP; ++e) {
            scores[e] = 1.0f / (1.0f + expf(-acc[e]));
            corr[e] = scores[e] + bias[e];
        }
        float gs[NGROUP];
#pragma unroll
        for (int g = 0; g < NGROUP; ++g) gs[g] = corr[2 * g] + corr[2 * g + 1];
        int g0 = 0;
#pragma unroll
        for (int g = 1; g < NGROUP; ++g) if (gs[g] > gs[g0]) g0 = g;
        int g1 = -1;
#pragma unroll
        for (int g = 0; g < NGROUP; ++g) {
            if (g == g0) continue;
            if (g1 < 0 || gs[g] > gs[g1]) g1 = g;
        }
        int e0 = -1;
#pragma unroll
        for (int e = 0; e < NEXP; ++e) {
            const int g = e >> 1;
            if (g != g0 && g != g1) continue;
            if (e0 < 0 || corr[e] > corr[e0]) e0 = e;
        }
        int e1 = -1;
#pragma unroll
        for (int e = 0; e < NEXP; ++e) {
            const int g = e >> 1;
            if ((g != g0 && g != g1) || e == e0) continue;
            if (e1 < 0 || corr[e] > corr[e1]) e1 = e;
        }
        float w0 = scores[e0], w1 = scores[e1];
        const float inv = 1.0f / (w0 + w1 + 1e-20f);
        w0 *= inv * SCALE;
        w1 *= inv * SCALE;
        const int p0 = atomicAdd(&ecnt[e0], 1);
        elist[e0 * T_TOK + p0] = t * 2 + 0;
        elist_w[e0 * T_TOK + p0] = w0;
        const int p1 = atomicAdd(&ecnt[e1], 1);
        elist[e1 * T_TOK + p1] = t * 2 + 1;
        elist_w[e1 * T_TOK + p1] = w1;
    }
}

__global__ __launch_bounds__(256)
void gemm1_fb(const float* __restrict__ x, const float* __restrict__ wg_all,
              const float* __restrict__ wu_all, const int* __restrict__ ecnt,
              const int* __restrict__ elist, float* __restrict__ act) {
    const int e = blockIdx.z;
    const int cnt = ecnt[e];
    const int row0 = blockIdx.x * 64;
    if (row0 >= cnt) return;
    const int col0 = blockIdx.y * 64;
    __shared__ __align__(16) float xs[64 * 64], gsm[64 * 64], usm[64 * 64];
    const int tid = threadIdx.x, lane = tid & 63, wv = tid >> 6;
    const int wr = wv >> 1, wc = wv & 1;
    const int laneR = lane & 15, laneQ = lane >> 4;
    const int* el = elist + e * T_TOK;
    const float* xrow[4]; const float* grow[4]; const float* urow[4];
    int coff[4], ldso[4];
#pragma unroll
    for (int l = 0; l < 4; ++l) {
        const int ci = tid + l * 256;
        const int row = ci >> 4;
        const int c = (ci & 15) ^ (row & 15);
        coff[l] = c * 4; ldso[l] = ci * 16;
        const int rr = row0 + row;
        const int v = (rr < cnt) ? el[rr] : 0;
        xrow[l] = x + (size_t)(v >> 1) * H_DIM;
        grow[l] = wg_all + (size_t)e * I_DIM * H_DIM + (size_t)(col0 + row) * H_DIM;
        urow[l] = wu_all + (size_t)e * I_DIM * H_DIM + (size_t)(col0 + row) * H_DIM;
    }
    f32x4 ag[2][2], au[2][2];
#pragma unroll
    for (int m = 0; m < 2; ++m)
#pragma unroll
        for (int n = 0; n < 2; ++n) { ag[m][n] = (f32x4)0.0f; au[m][n] = (f32x4)0.0f; }
    for (int k0 = 0; k0 < H_DIM; k0 += 64) {
        __syncthreads();
#pragma unroll
        for (int l = 0; l < 4; ++l) {
            gl_lds16((char*)xs + ldso[l], xrow[l] + k0 + coff[l]);
            gl_lds16((char*)gsm + ldso[l], grow[l] + k0 + coff[l]);
            gl_lds16((char*)usm + ldso[l], urow[l] + k0 + coff[l]);
        }
        __syncthreads();
#pragma unroll
        for (int ks = 0; ks < 2; ++ks) {
            const int off1 = ((ks * 128 + laneQ * 32) ^ (laneR << 4));
            bf16x8 xh[2], xl[2];
#pragma unroll
            for (int m = 0; m < 2; ++m)
                frag_ld(xs, wr * 32 + m * 16 + laneR, off1, xh[m], xl[m]);
            bf16x8 gh[2], gl[2], uh[2], ul[2];
#pragma unroll
            for (int n = 0; n < 2; ++n) {
                frag_ld(gsm, wc * 32 + n * 16 + laneR, off1, gh[n], gl[n]);
                frag_ld(usm, wc * 32 + n * 16 + laneR, off1, uh[n], ul[n]);
            }
#pragma unroll
            for (int m = 0; m < 2; ++m)
#pragma unroll
                for (int n = 0; n < 2; ++n) {
                    ag[m][n] = mmac3(xh[m], xl[m], gh[n], gl[n], ag[m][n]);
                    au[m][n] = mmac3(xh[m], xl[m], uh[n], ul[n], au[m][n]);
                }
        }
    }
#pragma unroll
    for (int m = 0; m < 2; ++m) {
        const int rl = wr * 32 + m * 16 + laneQ * 4;
#pragma unroll
        for (int j = 0; j < 4; ++j) {
            const int rr = row0 + rl + j;
            if (rr >= cnt) continue;
            const int v = el[rr];
            float* arow = act + (size_t)v * I_DIM;
#pragma unroll
            for (int n = 0; n < 2; ++n) {
                const int col = col0 + wc * 32 + n * 16 + laneR;
                const float g = ag[m][n][j];
                const float u = au[m][n][j];
                arow[col] = (g / (1.0f + __expf(-g))) * u;
            }
        }
    }
}

__global__ __launch_bounds__(256)
void gemm2_fb(const float* __restrict__ act, const float* __restrict__ wd_all,
              const int* __restrict__ ecnt, const int* __restrict__ elist,
              const float* __restrict__ elist_w, float* __restrict__ out) {
    const int e = blockIdx.z;
    const int cnt = ecnt[e];
    const int row0 = blockIdx.x * 64;
    if (row0 >= cnt) return;
    const int col0 = blockIdx.y * 64;
    __shared__ __align__(16) float as[64 * 64], dsm[64 * 64];
    const int tid = threadIdx.x, lane = tid & 63, wv = tid >> 6;
    const int wr = wv >> 1, wc = wv & 1;
    const int laneR = lane & 15, laneQ = lane >> 4;
    const int* el = elist + e * T_TOK;
    const float* elw = elist_w + e * T_TOK;
    const float* arow[4]; const float* drow[4];
    int coff[4], ldso[4];
#pragma unroll
    for (int l = 0; l < 4; ++l) {
        const int ci = tid + l * 256;
        const int row = ci >> 4;
        const int c = (ci & 15) ^ (row & 15);
        coff[l] = c * 4; ldso[l] = ci * 16;
        const int rr = row0 + row;
        const int v = (rr < cnt) ? el[rr] : 0;
        arow[l] = act + (size_t)v * I_DIM;
        drow[l] = wd_all + (size_t)e * H_DIM * I_DIM + (size_t)(col0 + row) * I_DIM;
    }
    f32x4 acc[2][2];
#pragma unroll
    for (int m = 0; m < 2; ++m)
#pragma unroll
        for (int n = 0; n < 2; ++n) acc[m][n] = (f32x4)0.0f;
    for (int k0 = 0; k0 < I_DIM; k0 += 64) {
        __syncthreads();
#pragma unroll
        for (int l = 0; l < 4; ++l) {
            gl_lds16((char*)as + ldso[l], arow[l] + k0 + coff[l]);
            gl_lds16((char*)dsm + ldso[l], drow[l] + k0 + coff[l]);
        }
        __syncthreads();
#pragma unroll
        for (int ks = 0; ks < 2; ++ks) {
            const int off1 = ((ks * 128 + laneQ * 32) ^ (laneR << 4));
            bf16x8 ah[2], al[2];
#pragma unroll
            for (int m = 0; m < 2; ++m)
                frag_ld(as, wr * 32 + m * 16 + laneR, off1, ah[m], al[m]);
            bf16x8 bh[2], bl[2];
#pragma unroll
            for (int n = 0; n < 2; ++n)
                frag_ld(dsm, wc * 32 + n * 16 + laneR, off1, bh[n], bl[n]);
#pragma unroll
            for (int m = 0; m < 2; ++m)
#pragma unroll
                for (int n = 0; n < 2; ++n)
                    acc[m][n] = mmac3(ah[m], al[m], bh[n], bl[n], acc[m][n]);
        }
    }
#pragma unroll
    for (int m = 0; m < 2; ++m) {
        const int rl = wr * 32 + m * 16 + laneQ * 4;
#pragma unroll
        for (int j = 0; j < 4; ++j) {
            const int rr = row0 + rl + j;
            if (rr >= cnt) continue;
            const int v = el[rr];
            const float w = elw[rr];
            float* orow = out + (size_t)(v >> 1) * H_DIM;
#pragma unroll
            for (int n = 0; n < 2; ++n) {
                const int col = col0 + wc * 32 + n * 16 + laneR;
                atomicAdd(&orow[col], w * acc[m][n][j]);
            }
        }
    }
}

// ---------------------------------------------------------------------------
extern "C" void kernel_launch(void* const* d_in, const int* in_sizes, int n_in,
                              void* d_out, int out_size, void* d_ws, size_t ws_size,
                              hipStream_t stream) {
    const float* x    = (const float*)d_in[0];
    const float* gw   = (const float*)d_in[1];
    const float* bias = (const float*)d_in[2];
    const float* wg   = (const float*)d_in[3];
    const float* wu   = (const float*)d_in[4];
    const float* wd   = (const float*)d_in[5];
    float* out = (float*)d_out;

    char* ws = (char*)d_ws;
    int*   ecnt    = (int*)(ws + OFF_ECNT);
    int*   elist   = (int*)(ws + OFF_ELIST);
    float* elist_w = (float*)(ws + OFF_EW);

    (void)hipMemsetAsync(ecnt, 0, 64, stream);
    (void)hipMemsetAsync(out, 0, (size_t)out_size * sizeof(float), stream);

    if (ws_size >= WS_NEED) {
        short* xh   = (short*)(ws + OFF_XH);
        short* xl   = (short*)(ws + OFF_XL);
        short* wgh  = (short*)(ws + OFF_WGH);
        short* wgl  = (short*)(ws + OFF_WGL);
        short* wuh  = (short*)(ws + OFF_WUH);
        short* wul  = (short*)(ws + OFF_WUL);
        short* wdh  = (short*)(ws + OFF_WDH);
        short* wdl  = (short*)(ws + OFF_WDL);
        short* acth = (short*)(ws + OFF_ACTH);
        short* actl = (short*)(ws + OFF_ACTL);

        const int nW = NEXP * I_DIM * H_DIM;   // 4,194,304 per tensor
        cvt_w_kernel<<<nW / 1024, 256, 0, stream>>>(wg, wgh, wgl, nW);
        cvt_w_kernel<<<nW / 1024, 256, 0, stream>>>(wu, wuh, wul, nW);
        cvt_w_kernel<<<nW / 1024, 256, 0, stream>>>(wd, wdh, wdl, nW);
        cvt_x_gate<<<T_TOK, 256, 0, stream>>>(x, gw, bias, xh, xl, ecnt, elist, elist_w);
        gemm1_planar<<<dim3(T_TOK / 64, I_DIM / 64, NEXP), 256, 0, stream>>>(
            xh, xl, wgh, wgl, wuh, wul, ecnt, elist, acth, actl);
        gemm2_planar<<<dim3(T_TOK / 64, H_DIM / 64, NEXP), 256, 0, stream>>>(
            acth, actl, wdh, wdl, ecnt, elist, elist_w, out);
    } else {
        float* act = (float*)(ws + OFF_ACT_FB);
        gate_kernel<<<T_TOK / 4, 256, 0, stream>>>(x, gw, bias, ecnt, elist, elist_w);
        gemm1_fb<<<dim3(T_TOK / 64, I_DIM / 64, NEXP), 256, 0, stream>>>(
            x, wg, wu, ecnt, elist, act);
        gemm2_fb<<<dim3(T_TOK / 64, H_DIM / 64, NEXP), 256, 0, stream>>>(
            act, wd, ecnt, elist, elist_w, out);
    }
}

// Round 9
// 299.466 us; speedup vs baseline: 3.8141x; 1.2477x over previous
//
#include <hip/hip_runtime.h>
#include <hip/hip_bf16.h>
#include <math.h>

// Problem constants (fixed by the reference)
#define H_DIM   1024
#define I_DIM   512
#define NEXP    8
#define NGROUP  4
#define T_TOK   4096
#define NPAIR   8192
#define SCALE   1.0f

typedef float f32x4 __attribute__((ext_vector_type(4)));
typedef short bf16x8 __attribute__((ext_vector_type(8)));
typedef short s16x4 __attribute__((ext_vector_type(4)));
typedef unsigned int u32;

// ---------------- workspace layout (fast path), bytes ----------------
static constexpr size_t OFF_ECNT  = 0;                        // 64 B
static constexpr size_t OFF_ELIST = 1024;                     // 128 KB
static constexpr size_t OFF_EW    = OFF_ELIST + (size_t)NEXP * T_TOK * 4;
static constexpr size_t OFF_SEL   = 512 * 1024;               // int[4096]
static constexpr size_t OFF_SELW  = 512 * 1024 + 64 * 1024;   // float2[4096]
static constexpr size_t MB = 1u << 20;
static constexpr size_t OFF_XH   = 1 * MB;   // 4096x1024 bf16 = 8 MB
static constexpr size_t OFF_XL   = 9 * MB;
static constexpr size_t OFF_WGH  = 17 * MB;  // 8x512x1024 bf16 = 8 MB each
static constexpr size_t OFF_WGL  = 25 * MB;
static constexpr size_t OFF_WUH  = 33 * MB;
static constexpr size_t OFF_WUL  = 41 * MB;
static constexpr size_t OFF_WDH  = 49 * MB;  // 8x1024x512
static constexpr size_t OFF_WDL  = 57 * MB;
static constexpr size_t OFF_ACTH = 65 * MB;  // 8192x512 bf16 = 8 MB
static constexpr size_t OFF_ACTL = 73 * MB;
static constexpr size_t WS_NEED  = 81 * MB;
// fallback (R2) layout
static constexpr size_t OFF_ACT_FB = 1 * MB; // 8192x512 f32 = 16.8 MB

// ---------------------------------------------------------------------------
__device__ __forceinline__ void gl_lds16(void* lds, const void* g) {
    __builtin_amdgcn_global_load_lds(
        (const __attribute__((address_space(1))) u32*)g,
        (__attribute__((address_space(3))) u32*)lds, 16, 0, 0);
}

__device__ __forceinline__ void split1(float v, short& h, short& l) {
    const u32 b = __float_as_uint(v);
    h = (short)(b >> 16);
    const float r = v - __uint_as_float(b & 0xffff0000u);
    l = (short)(__float_as_uint(r) >> 16);
}

// split-bf16 triple MFMA: acc += Ah*Bh + Ah*Bl + Al*Bh
__device__ __forceinline__ f32x4 mmac3(bf16x8 ah, bf16x8 al, bf16x8 bh,
                                       bf16x8 bl, f32x4 c) {
    c = __builtin_amdgcn_mfma_f32_16x16x32_bf16(ah, bh, c, 0, 0, 0);
    c = __builtin_amdgcn_mfma_f32_16x16x32_bf16(ah, bl, c, 0, 0, 0);
    c = __builtin_amdgcn_mfma_f32_16x16x32_bf16(al, bh, c, 0, 0, 0);
    return c;
}

// read one bf16x8 fragment from a swizzled [64][64] bf16 LDS tile (128B rows)
__device__ __forceinline__ bf16x8 frag16(const short* tile, int row, int boff) {
    return *(const bf16x8*)((const char*)tile + row * 128 + boff);
}

// ---------------------------------------------------------------------------
// Fast path: x conversion to hi/lo planes + gate routing (contention-free:
// per-token sel/selw writes, no atomics)
// ---------------------------------------------------------------------------
__global__ __launch_bounds__(256)
void cvt_x_gate(const float* __restrict__ x,
                const float* __restrict__ gw,
                const float* __restrict__ bias,
                short* __restrict__ xh, short* __restrict__ xl,
                int* __restrict__ sel, float2* __restrict__ selw) {
    const int t = blockIdx.x;
    const int tid = threadIdx.x;
    const int lane = tid & 63;
    const int wv = tid >> 6;
    const int h = tid * 4;

    const f32x4 xv = *(const f32x4*)(x + (size_t)t * H_DIM + h);
    s16x4 hv, lv;
#pragma unroll
    for (int j = 0; j < 4; ++j) {
        short hh, ll;
        split1(xv[j], hh, ll);
        hv[j] = hh;
        lv[j] = ll;
    }
    *(s16x4*)(xh + (size_t)t * H_DIM + h) = hv;
    *(s16x4*)(xl + (size_t)t * H_DIM + h) = lv;

    float acc[NEXP];
#pragma unroll
    for (int e = 0; e < NEXP; ++e) {
        const f32x4 g = *(const f32x4*)(gw + e * H_DIM + h);
        float a = xv[0] * g[0];
        a = fmaf(xv[1], g[1], a);
        a = fmaf(xv[2], g[2], a);
        a = fmaf(xv[3], g[3], a);
        acc[e] = a;
    }
#pragma unroll
    for (int e = 0; e < NEXP; ++e) {
        float v = acc[e];
#pragma unroll
        for (int s = 32; s > 0; s >>= 1) v += __shfl_xor(v, s, 64);
        acc[e] = v;
    }
    __shared__ float red[4][NEXP];
    if (lane == 0) {
#pragma unroll
        for (int e = 0; e < NEXP; ++e) red[wv][e] = acc[e];
    }
    __syncthreads();
    if (tid == 0) {
        float scores[NEXP], corr[NEXP];
#pragma unroll
        for (int e = 0; e < NEXP; ++e) {
            const float s = red[0][e] + red[1][e] + red[2][e] + red[3][e];
            scores[e] = 1.0f / (1.0f + expf(-s));
            corr[e] = scores[e] + bias[e];
        }
        float gs[NGROUP];
#pragma unroll
        for (int g = 0; g < NGROUP; ++g) gs[g] = corr[2 * g] + corr[2 * g + 1];
        int g0 = 0;
#pragma unroll
        for (int g = 1; g < NGROUP; ++g) if (gs[g] > gs[g0]) g0 = g;
        int g1 = -1;
#pragma unroll
        for (int g = 0; g < NGROUP; ++g) {
            if (g == g0) continue;
            if (g1 < 0 || gs[g] > gs[g1]) g1 = g;
        }
        int e0 = -1;
#pragma unroll
        for (int e = 0; e < NEXP; ++e) {
            const int g = e >> 1;
            if (g != g0 && g != g1) continue;
            if (e0 < 0 || corr[e] > corr[e0]) e0 = e;
        }
        int e1 = -1;
#pragma unroll
        for (int e = 0; e < NEXP; ++e) {
            const int g = e >> 1;
            if ((g != g0 && g != g1) || e == e0) continue;
            if (e1 < 0 || corr[e] > corr[e1]) e1 = e;
        }
        float w0 = scores[e0], w1 = scores[e1];
        const float inv = 1.0f / (w0 + w1 + 1e-20f);
        w0 *= inv * SCALE;
        w1 *= inv * SCALE;
        sel[t] = e0 | (e1 << 8);
        selw[t] = make_float2(w0, w1);
    }
}

// ---------------------------------------------------------------------------
// Deterministic per-expert list compaction (token-ordered), 8 blocks.
// ---------------------------------------------------------------------------
__global__ __launch_bounds__(256)
void build_lists(const int* __restrict__ sel, const float2* __restrict__ selw,
                 int* __restrict__ ecnt, int* __restrict__ elist,
                 float* __restrict__ elist_w) {
    const int e = blockIdx.x;
    const int tid = threadIdx.x;
    const int lane = tid & 63;
    const int wv = tid >> 6;
    const int base = tid * (T_TOK / 256);   // 16 tokens per thread

    int c = 0;
#pragma unroll
    for (int i = 0; i < T_TOK / 256; ++i) {
        const int s = sel[base + i];
        if ((s & 0xff) == e || ((s >> 8) & 0xff) == e) ++c;
    }
    // inclusive scan within wave
    int v = c;
#pragma unroll
    for (int d = 1; d < 64; d <<= 1) {
        const int o = __shfl_up(v, d, 64);
        if (lane >= d) v += o;
    }
    __shared__ int wsum[4];
    if (lane == 63) wsum[wv] = v;
    __syncthreads();
    int waveoff = 0;
#pragma unroll
    for (int w = 0; w < 4; ++w) waveoff += (w < wv) ? wsum[w] : 0;
    int p = waveoff + v - c;   // exclusive block-wide offset
#pragma unroll
    for (int i = 0; i < T_TOK / 256; ++i) {
        const int t = base + i;
        const int s = sel[t];
        const float2 w2 = selw[t];
        if ((s & 0xff) == e) {
            elist[e * T_TOK + p] = t * 2;
            elist_w[e * T_TOK + p] = w2.x;
            ++p;
        } else if (((s >> 8) & 0xff) == e) {
            elist[e * T_TOK + p] = t * 2 + 1;
            elist_w[e * T_TOK + p] = w2.y;
            ++p;
        }
    }
    if (tid == 0) ecnt[e] = wsum[0] + wsum[1] + wsum[2] + wsum[3];
}

// elementwise fp32 -> bf16 hi/lo planes (weights); n multiple of 1024
__global__ __launch_bounds__(256)
void cvt_w_kernel(const float* __restrict__ src, short* __restrict__ h,
                  short* __restrict__ l, int n) {
    const int i = (blockIdx.x * 256 + threadIdx.x) * 4;
    if (i >= n) return;
    const f32x4 v = *(const f32x4*)(src + i);
    s16x4 hv, lv;
#pragma unroll
    for (int j = 0; j < 4; ++j) {
        short hh, ll;
        split1(v[j], hh, ll);
        hv[j] = hh;
        lv[j] = ll;
    }
    *(s16x4*)(h + i) = hv;
    *(s16x4*)(l + i) = lv;
}

// ---------------------------------------------------------------------------
// GEMM1 planar: gathered x (hi/lo) vs gate/up (hi/lo), fused silu*up,
// act written as hi/lo bf16 planes. 4 waves (2x2), tile 64x64, BK=64.
// ---------------------------------------------------------------------------
__global__ __launch_bounds__(256)
void gemm1_planar(const short* __restrict__ xh, const short* __restrict__ xl,
                  const short* __restrict__ wgh, const short* __restrict__ wgl,
                  const short* __restrict__ wuh, const short* __restrict__ wul,
                  const int* __restrict__ ecnt, const int* __restrict__ elist,
                  short* __restrict__ acth, short* __restrict__ actl) {
    const int e = blockIdx.z;
    const int cnt = ecnt[e];
    const int row0 = blockIdx.x * 64;
    if (row0 >= cnt) return;
    const int col0 = blockIdx.y * 64;

    __shared__ __align__(16) short xhb[4096], xlb[4096];
    __shared__ __align__(16) short ghb[4096], glb[4096];
    __shared__ __align__(16) short uhb[4096], ulb[4096];

    const int tid = threadIdx.x, lane = tid & 63, wv = tid >> 6;
    const int wr = wv >> 1, wc = wv & 1;
    const int laneR = lane & 15, laneQ = lane >> 4;
    const int* el = elist + e * T_TOK;

    size_t xoff[2], woff[2];
    int ldso[2];
#pragma unroll
    for (int l = 0; l < 2; ++l) {
        const int ci = tid + l * 256;
        const int row = ci >> 3;
        const int c = (ci & 7) ^ (row & 7);     // pre-swizzled source chunk
        ldso[l] = ci * 16;
        const int rr = row0 + row;
        const int v = (rr < cnt) ? el[rr] : 0;
        xoff[l] = (size_t)(v >> 1) * H_DIM + c * 8;
        woff[l] = ((size_t)e * I_DIM + col0 + row) * H_DIM + c * 8;
    }

    f32x4 ag[2][2], au[2][2];
#pragma unroll
    for (int m = 0; m < 2; ++m)
#pragma unroll
        for (int n = 0; n < 2; ++n) { ag[m][n] = (f32x4)0.0f; au[m][n] = (f32x4)0.0f; }

    for (int k0 = 0; k0 < H_DIM; k0 += 64) {
        __syncthreads();
#pragma unroll
        for (int l = 0; l < 2; ++l) {
            gl_lds16((char*)xhb + ldso[l], xh + xoff[l] + k0);
            gl_lds16((char*)xlb + ldso[l], xl + xoff[l] + k0);
            gl_lds16((char*)ghb + ldso[l], wgh + woff[l] + k0);
            gl_lds16((char*)glb + ldso[l], wgl + woff[l] + k0);
            gl_lds16((char*)uhb + ldso[l], wuh + woff[l] + k0);
            gl_lds16((char*)ulb + ldso[l], wul + woff[l] + k0);
        }
        __syncthreads();

#pragma unroll
        for (int ks = 0; ks < 2; ++ks) {
            const int boff = (ks * 64 + laneQ * 16) ^ ((laneR & 7) << 4);
            bf16x8 xh_[2], xl_[2];
#pragma unroll
            for (int m = 0; m < 2; ++m) {
                const int r = wr * 32 + m * 16 + laneR;
                xh_[m] = frag16(xhb, r, boff);
                xl_[m] = frag16(xlb, r, boff);
            }
            bf16x8 gh_[2], gl_[2], uh_[2], ul_[2];
#pragma unroll
            for (int n = 0; n < 2; ++n) {
                const int r = wc * 32 + n * 16 + laneR;
                gh_[n] = frag16(ghb, r, boff);
                gl_[n] = frag16(glb, r, boff);
                uh_[n] = frag16(uhb, r, boff);
                ul_[n] = frag16(ulb, r, boff);
            }
#pragma unroll
            for (int m = 0; m < 2; ++m)
#pragma unroll
                for (int n = 0; n < 2; ++n) {
                    ag[m][n] = mmac3(xh_[m], xl_[m], gh_[n], gl_[n], ag[m][n]);
                    au[m][n] = mmac3(xh_[m], xl_[m], uh_[n], ul_[n], au[m][n]);
                }
        }
    }

    // C/D map: col=lane&15, row=(lane>>4)*4+j (verified in R2)
#pragma unroll
    for (int m = 0; m < 2; ++m) {
        const int rl = wr * 32 + m * 16 + laneQ * 4;
#pragma unroll
        for (int j = 0; j < 4; ++j) {
            const int rr = row0 + rl + j;
            if (rr >= cnt) continue;
            const int v = el[rr];
#pragma unroll
            for (int n = 0; n < 2; ++n) {
                const int col = col0 + wc * 32 + n * 16 + laneR;
                const float g = ag[m][n][j];
                const float u = au[m][n][j];
                const float val = (g / (1.0f + __expf(-g))) * u;
                short hh, ll;
                split1(val, hh, ll);
                acth[(size_t)v * I_DIM + col] = hh;
                actl[(size_t)v * I_DIM + col] = ll;
            }
        }
    }
}

// ---------------------------------------------------------------------------
// GEMM2 planar: act (hi/lo) vs down_proj (hi/lo), scaled atomicAdd into out.
// ---------------------------------------------------------------------------
__global__ __launch_bounds__(256)
void gemm2_planar(const short* __restrict__ acth, const short* __restrict__ actl,
                  const short* __restrict__ wdh, const short* __restrict__ wdl,
                  const int* __restrict__ ecnt, const int* __restrict__ elist,
                  const float* __restrict__ elist_w, float* __restrict__ out) {
    const int e = blockIdx.z;
    const int cnt = ecnt[e];
    const int row0 = blockIdx.x * 64;
    if (row0 >= cnt) return;
    const int col0 = blockIdx.y * 64;

    __shared__ __align__(16) short ahb[4096], alb[4096];
    __shared__ __align__(16) short dhb[4096], dlb[4096];

    const int tid = threadIdx.x, lane = tid & 63, wv = tid >> 6;
    const int wr = wv >> 1, wc = wv & 1;
    const int laneR = lane & 15, laneQ = lane >> 4;
    const int* el = elist + e * T_TOK;
    const float* elw = elist_w + e * T_TOK;

    size_t aoff[2], woff[2];
    int ldso[2];
#pragma unroll
    for (int l = 0; l < 2; ++l) {
        const int ci = tid + l * 256;
        const int row = ci >> 3;
        const int c = (ci & 7) ^ (row & 7);
        ldso[l] = ci * 16;
        const int rr = row0 + row;
        const int v = (rr < cnt) ? el[rr] : 0;
        aoff[l] = (size_t)v * I_DIM + c * 8;
        woff[l] = ((size_t)e * H_DIM + col0 + row) * I_DIM + c * 8;
    }

    f32x4 acc[2][2];
#pragma unroll
    for (int m = 0; m < 2; ++m)
#pragma unroll
        for (int n = 0; n < 2; ++n) acc[m][n] = (f32x4)0.0f;

    for (int k0 = 0; k0 < I_DIM; k0 += 64) {
        __syncthreads();
#pragma unroll
        for (int l = 0; l < 2; ++l) {
            gl_lds16((char*)ahb + ldso[l], acth + aoff[l] + k0);
            gl_lds16((char*)alb + ldso[l], actl + aoff[l] + k0);
            gl_lds16((char*)dhb + ldso[l], wdh + woff[l] + k0);
            gl_lds16((char*)dlb + ldso[l], wdl + woff[l] + k0);
        }
        __syncthreads();

#pragma unroll
        for (int ks = 0; ks < 2; ++ks) {
            const int boff = (ks * 64 + laneQ * 16) ^ ((laneR & 7) << 4);
            bf16x8 ah_[2], al_[2];
#pragma unroll
            for (int m = 0; m < 2; ++m) {
                const int r = wr * 32 + m * 16 + laneR;
                ah_[m] = frag16(ahb, r, boff);
                al_[m] = frag16(alb, r, boff);
            }
            bf16x8 bh_[2], bl_[2];
#pragma unroll
            for (int n = 0; n < 2; ++n) {
                const int r = wc * 32 + n * 16 + laneR;
                bh_[n] = frag16(dhb, r, boff);
                bl_[n] = frag16(dlb, r, boff);
            }
#pragma unroll
            for (int m = 0; m < 2; ++m)
#pragma unroll
                for (int n = 0; n < 2; ++n)
                    acc[m][n] = mmac3(ah_[m], al_[m], bh_[n], bl_[n], acc[m][n]);
        }
    }

#pragma unroll
    for (int m = 0; m < 2; ++m) {
        const int rl = wr * 32 + m * 16 + laneQ * 4;
#pragma unroll
        for (int j = 0; j < 4; ++j) {
            const int rr = row0 + rl + j;
            if (rr >= cnt) continue;
            const int v = el[rr];
            const float w = elw[rr];
            float* orow = out + (size_t)(v >> 1) * H_DIM;
#pragma unroll
            for (int n = 0; n < 2; ++n) {
                const int col = col0 + wc * 32 + n * 16 + laneR;
                atomicAdd(&orow[col], w * acc[m][n][j]);
            }
        }
    }
}

// ===========================================================================
// Fallback path (R2, verified): used only if ws_size < WS_NEED
// ===========================================================================
__device__ __forceinline__ void cvt8(const f32x4& a, const f32x4& b,
                                     bf16x8& hi, bf16x8& lo) {
#pragma unroll
    for (int j = 0; j < 4; ++j) {
        short hh, ll;
        split1(a[j], hh, ll);
        ((short*)&hi)[j] = hh;
        ((short*)&lo)[j] = ll;
    }
#pragma unroll
    for (int j = 0; j < 4; ++j) {
        short hh, ll;
        split1(b[j], hh, ll);
        ((short*)&hi)[4 + j] = hh;
        ((short*)&lo)[4 + j] = ll;
    }
}

__device__ __forceinline__ void frag_ld(const float* tile, int row, int off1,
                                        bf16x8& hi, bf16x8& lo) {
    const char* p = (const char*)tile + row * 256;
    const f32x4 a = *(const f32x4*)(p + off1);
    const f32x4 b = *(const f32x4*)(p + (off1 ^ 16));
    cvt8(a, b, hi, lo);
}

__global__ __launch_bounds__(256)
void gate_kernel(const float* __restrict__ x, const float* __restrict__ gw,
                 const float* __restrict__ bias, int* __restrict__ ecnt,
                 int* __restrict__ elist, float* __restrict__ elist_w) {
    const int wave = threadIdx.x >> 6;
    const int lane = threadIdx.x & 63;
    const int t = blockIdx.x * 4 + wave;
    if (t >= T_TOK) return;
    const float* xr = x + (size_t)t * H_DIM;
    float acc[NEXP];
#pragma unroll
    for (int e = 0; e < NEXP; ++e) acc[e] = 0.0f;
    for (int h = lane; h < H_DIM; h += 64) {
        const float xv = xr[h];
#pragma unroll
        for (int e = 0; e < NEXP; ++e) acc[e] = fmaf(xv, gw[e * H_DIM + h], acc[e]);
    }
#pragma unroll
    for (int e = 0; e < NEXP; ++e) {
        float v = acc[e];
#pragma unroll
        for (int s = 32; s > 0; s >>= 1) v += __shfl_xor(v, s, 64);
        acc[e] = v;
    }
    if (lane == 0) {
        float scores[NEXP], corr[NEXP];
#pragma unroll
        for (int e = 0; e < NEXP; ++e) {
            scores[e] = 1.0f / (1.0f + expf(-acc[e]));
            corr[e] = scores[e] + bias[e];
        }
        float gs[NGROUP];
#pragma unroll
        for (int g = 0; g < NGROUP; ++g) gs[g] = corr[2 * g] + corr[2 * g + 1];
        int g0 = 0;
#pragma unroll
        for (int g = 1; g < NGROUP; ++g) if (gs[g] > gs[g0]) g0 = g;
        int g1 = -1;
#pragma unroll
        for (int g = 0; g < NGROUP; ++g) {
            if (g == g0) continue;
            if (g1 < 0 || gs[g] > gs[g1]) g1 = g;
        }
        int e0 = -1;
#pragma unroll
        for (int e = 0; e < NEXP; ++e) {
            const int g = e >> 1;
            if (g != g0 && g != g1) continue;
            if (e0 < 0 || corr[e] > corr[e0]) e0 = e;
        }
        int e1 = -1;
#pragma unroll
        for (int e = 0; e < NEXP; ++e) {
            const int g = e >> 1;
            if ((g != g0 && g != g1) || e == e0) continue;
            if (e1 < 0 || corr[e] > corr[e1]) e1 = e;
        }
        float w0 = scores[e0], w1 = scores[e1];
        const float inv = 1.0f / (w0 + w1 + 1e-20f);
        w0 *= inv * SCALE;
        w1 *= inv * SCALE;
        const int p0 = atomicAdd(&ecnt[e0], 1);
        elist[e0 * T_TOK + p0] = t * 2 + 0;
        elist_w[e0 * T_TOK + p0] = w0;
        const int p1 = atomicAdd(&ecnt[e1], 1);
        elist[e1 * T_TOK + p1] = t * 2 + 1;
        elist_w[e1 * T_TOK + p1] = w1;
    }
}

__global__ __launch_bounds__(256)
void gemm1_fb(const float* __restrict__ x, const float* __restrict__ wg_all,
              const float* __restrict__ wu_all, const int* __restrict__ ecnt,
              const int* __restrict__ elist, float* __restrict__ act) {
    const int e = blockIdx.z;
    const int cnt = ecnt[e];
    const int row0 = blockIdx.x * 64;
    if (row0 >= cnt) return;
    const int col0 = blockIdx.y * 64;
    __shared__ __align__(16) float xs[64 * 64], gsm[64 * 64], usm[64 * 64];
    const int tid = threadIdx.x, lane = tid & 63, wv = tid >> 6;
    const int wr = wv >> 1, wc = wv & 1;
    const int laneR = lane & 15, laneQ = lane >> 4;
    const int* el = elist + e * T_TOK;
    const float* xrow[4]; const float* grow[4]; const float* urow[4];
    int coff[4], ldso[4];
#pragma unroll
    for (int l = 0; l < 4; ++l) {
        const int ci = tid + l * 256;
        const int row = ci >> 4;
        const int c = (ci & 15) ^ (row & 15);
        coff[l] = c * 4; ldso[l] = ci * 16;
        const int rr = row0 + row;
        const int v = (rr < cnt) ? el[rr] : 0;
        xrow[l] = x + (size_t)(v >> 1) * H_DIM;
        grow[l] = wg_all + (size_t)e * I_DIM * H_DIM + (size_t)(col0 + row) * H_DIM;
        urow[l] = wu_all + (size_t)e * I_DIM * H_DIM + (size_t)(col0 + row) * H_DIM;
    }
    f32x4 ag[2][2], au[2][2];
#pragma unroll
    for (int m = 0; m < 2; ++m)
#pragma unroll
        for (int n = 0; n < 2; ++n) { ag[m][n] = (f32x4)0.0f; au[m][n] = (f32x4)0.0f; }
    for (int k0 = 0; k0 < H_DIM; k0 += 64) {
        __syncthreads();
#pragma unroll
        for (int l = 0; l < 4; ++l) {
            gl_lds16((char*)xs + ldso[l], xrow[l] + k0 + coff[l]);
            gl_lds16((char*)gsm + ldso[l], grow[l] + k0 + coff[l]);
            gl_lds16((char*)usm + ldso[l], urow[l] + k0 + coff[l]);
        }
        __syncthreads();
#pragma unroll
        for (int ks = 0; ks < 2; ++ks) {
            const int off1 = ((ks * 128 + laneQ * 32) ^ (laneR << 4));
            bf16x8 xh[2], xl[2];
#pragma unroll
            for (int m = 0; m < 2; ++m)
                frag_ld(xs, wr * 32 + m * 16 + laneR, off1, xh[m], xl[m]);
            bf16x8 gh[2], gl[2], uh[2], ul[2];
#pragma unroll
            for (int n = 0; n < 2; ++n) {
                frag_ld(gsm, wc * 32 + n * 16 + laneR, off1, gh[n], gl[n]);
                frag_ld(usm, wc * 32 + n * 16 + laneR, off1, uh[n], ul[n]);
            }
#pragma unroll
            for (int m = 0; m < 2; ++m)
#pragma unroll
                for (int n = 0; n < 2; ++n) {
                    ag[m][n] = mmac3(xh[m], xl[m], gh[n], gl[n], ag[m][n]);
                    au[m][n] = mmac3(xh[m], xl[m], uh[n], ul[n], au[m][n]);
                }
        }
    }
#pragma unroll
    for (int m = 0; m < 2; ++m) {
        const int rl = wr * 32 + m * 16 + laneQ * 4;
#pragma unroll
        for (int j = 0; j < 4; ++j) {
            const int rr = row0 + rl + j;
            if (rr >= cnt) continue;
            const int v = el[rr];
            float* arow = act + (size_t)v * I_DIM;
#pragma unroll
            for (int n = 0; n < 2; ++n) {
                const int col = col0 + wc * 32 + n * 16 + laneR;
                const float g = ag[m][n][j];
                const float u = au[m][n][j];
                arow[col] = (g / (1.0f + __expf(-g))) * u;
            }
        }
    }
}

__global__ __launch_bounds__(256)
void gemm2_fb(const float* __restrict__ act, const float* __restrict__ wd_all,
              const int* __restrict__ ecnt, const int* __restrict__ elist,
              const float* __restrict__ elist_w, float* __restrict__ out) {
    const int e = blockIdx.z;
    const int cnt = ecnt[e];
    const int row0 = blockIdx.x * 64;
    if (row0 >= cnt) return;
    const int col0 = blockIdx.y * 64;
    __shared__ __align__(16) float as[64 * 64], dsm[64 * 64];
    const int tid = threadIdx.x, lane = tid & 63, wv = tid >> 6;
    const int wr = wv >> 1, wc = wv & 1;
    const int laneR = lane & 15, laneQ = lane >> 4;
    const int* el = elist + e * T_TOK;
    const float* elw = elist_w + e * T_TOK;
    const float* arow[4]; const float* drow[4];
    int coff[4], ldso[4];
#pragma unroll
    for (int l = 0; l < 4; ++l) {
        const int ci = tid + l * 256;
        const int row = ci >> 4;
        const int c = (ci & 15) ^ (row & 15);
        coff[l] = c * 4; ldso[l] = ci * 16;
        const int rr = row0 + row;
        const int v = (rr < cnt) ? el[rr] : 0;
        arow[l] = act + (size_t)v * I_DIM;
        drow[l] = wd_all + (size_t)e * H_DIM * I_DIM + (size_t)(col0 + row) * I_DIM;
    }
    f32x4 acc[2][2];
#pragma unroll
    for (int m = 0; m < 2; ++m)
#pragma unroll
        for (int n = 0; n < 2; ++n) acc[m][n] = (f32x4)0.0f;
    for (int k0 = 0; k0 < I_DIM; k0 += 64) {
        __syncthreads();
#pragma unroll
        for (int l = 0; l < 4; ++l) {
            gl_lds16((char*)as + ldso[l], arow[l] + k0 + coff[l]);
            gl_lds16((char*)dsm + ldso[l], drow[l] + k0 + coff[l]);
        }
        __syncthreads();
#pragma unroll
        for (int ks = 0; ks < 2; ++ks) {
            const int off1 = ((ks * 128 + laneQ * 32) ^ (laneR << 4));
            bf16x8 ah[2], al[2];
#pragma unroll
            for (int m = 0; m < 2; ++m)
                frag_ld(as, wr * 32 + m * 16 + laneR, off1, ah[m], al[m]);
            bf16x8 bh[2], bl[2];
#pragma unroll
            for (int n = 0; n < 2; ++n)
                frag_ld(dsm, wc * 32 + n * 16 + laneR, off1, bh[n], bl[n]);
#pragma unroll
            for (int m = 0; m < 2; ++m)
#pragma unroll
                for (int n = 0; n < 2; ++n)
                    acc[m][n] = mmac3(ah[m], al[m], bh[n], bl[n], acc[m][n]);
        }
    }
#pragma unroll
    for (int m = 0; m < 2; ++m) {
        const int rl = wr * 32 + m * 16 + laneQ * 4;
#pragma unroll
        for (int j = 0; j < 4; ++j) {
            const int rr = row0 + rl + j;
            if (rr >= cnt) continue;
            const int v = el[rr];
            const float w = elw[rr];
            float* orow = out + (size_t)(v >> 1) * H_DIM;
#pragma unroll
            for (int n = 0; n < 2; ++n) {
                const int col = col0 + wc * 32 + n * 16 + laneR;
                atomicAdd(&orow[col], w * acc[m][n][j]);
            }
        }
    }
}

// ---------------------------------------------------------------------------
extern "C" void kernel_launch(void* const* d_in, const int* in_sizes, int n_in,
                              void* d_out, int out_size, void* d_ws, size_t ws_size,
                              hipStream_t stream) {
    const float* x    = (const float*)d_in[0];
    const float* gw   = (const float*)d_in[1];
    const float* bias = (const float*)d_in[2];
    const float* wg   = (const float*)d_in[3];
    const float* wu   = (const float*)d_in[4];
    const float* wd   = (const float*)d_in[5];
    float* out = (float*)d_out;

    char* ws = (char*)d_ws;
    int*   ecnt    = (int*)(ws + OFF_ECNT);
    int*   elist   = (int*)(ws + OFF_ELIST);
    float* elist_w = (float*)(ws + OFF_EW);

    (void)hipMemsetAsync(ecnt, 0, 64, stream);
    (void)hipMemsetAsync(out, 0, (size_t)out_size * sizeof(float), stream);

    if (ws_size >= WS_NEED) {
        int*    sel  = (int*)(ws + OFF_SEL);
        float2* selw = (float2*)(ws + OFF_SELW);
        short* xh   = (short*)(ws + OFF_XH);
        short* xl   = (short*)(ws + OFF_XL);
        short* wgh  = (short*)(ws + OFF_WGH);
        short* wgl  = (short*)(ws + OFF_WGL);
        short* wuh  = (short*)(ws + OFF_WUH);
        short* wul  = (short*)(ws + OFF_WUL);
        short* wdh  = (short*)(ws + OFF_WDH);
        short* wdl  = (short*)(ws + OFF_WDL);
        short* acth = (short*)(ws + OFF_ACTH);
        short* actl = (short*)(ws + OFF_ACTL);

        const int nW = NEXP * I_DIM * H_DIM;   // 4,194,304 per tensor
        cvt_w_kernel<<<nW / 1024, 256, 0, stream>>>(wg, wgh, wgl, nW);
        cvt_w_kernel<<<nW / 1024, 256, 0, stream>>>(wu, wuh, wul, nW);
        cvt_w_kernel<<<nW / 1024, 256, 0, stream>>>(wd, wdh, wdl, nW);
        cvt_x_gate<<<T_TOK, 256, 0, stream>>>(x, gw, bias, xh, xl, sel, selw);
        build_lists<<<NEXP, 256, 0, stream>>>(sel, selw, ecnt, elist, elist_w);
        gemm1_planar<<<dim3(T_TOK / 64, I_DIM / 64, NEXP), 256, 0, stream>>>(
            xh, xl, wgh, wgl, wuh, wul, ecnt, elist, acth, actl);
        gemm2_planar<<<dim3(T_TOK / 64, H_DIM / 64, NEXP), 256, 0, stream>>>(
            acth, actl, wdh, wdl, ecnt, elist, elist_w, out);
    } else {
        float* act = (float*)(ws + OFF_ACT_FB);
        gate_kernel<<<T_TOK / 4, 256, 0, stream>>>(x, gw, bias, ecnt, elist, elist_w);
        gemm1_fb<<<dim3(T_TOK / 64, I_DIM / 64, NEXP), 256, 0, stream>>>(
            x, wg, wu, ecnt, elist, act);
        gemm2_fb<<<dim3(T_TOK / 64, H_DIM / 64, NEXP), 256, 0, stream>>>(
            act, wd, ecnt, elist, elist_w, out);
    }
}